// Round 5
// baseline (2195.099 us; speedup 1.0000x reference)
//
#include <hip/hip_runtime.h>
#include <math.h>

#define D_MODEL 1024
#define NUM_HEADS 16
#define DK 64
#define BATCH 2
#define SEQ 2048

using f32x4  = __attribute__((ext_vector_type(4))) float;
using bf16x8 = __attribute__((ext_vector_type(8))) short;
using us8    = __attribute__((ext_vector_type(8))) unsigned short;

__device__ __forceinline__ unsigned short f2b(float x) {  // fp32 -> bf16 RNE
    unsigned u = __float_as_uint(x);
    return (unsigned short)((u + 0x7FFF + ((u >> 16) & 1)) >> 16);
}
__device__ __forceinline__ float b2f(unsigned short h) {
    return __uint_as_float(((unsigned)h) << 16);
}
__device__ __forceinline__ void gl_lds16(const unsigned short* g, unsigned short* l) {
    __builtin_amdgcn_global_load_lds(
        (const __attribute__((address_space(1))) void*)g,
        (__attribute__((address_space(3))) void*)l, 16, 0, 0);
}

// ---------------------------------------------------------------------------
// fp32 [rows][1024] -> bf16 [rows][3072] along K, with the GEMM's LDS row-XOR
// swizzle baked in (stored 16B block ss holds logical block ss ^ (row&7)).
// LOSEG selects which K-third carries the lo residual:
//   activations LOSEG=1 -> [hi | lo | hi]
//   weights     LOSEG=2 -> [hi | hi | lo]
// so A2 . W2 = hi.hi + lo.hi + hi.lo  (the correct 3-term hi/lo product).
// ---------------------------------------------------------------------------
template <int LOSEG>
__global__ __launch_bounds__(256) void conv_hilo_kernel(
    const float* __restrict__ src, unsigned short* __restrict__ dst, int rows)
{
    const int id = blockIdx.x * 256 + threadIdx.x;
    if (id >= rows * 384) return;
    const int row = id / 384;
    const int s   = id - row * 384;          // stored 16B-block index in [0,384)
    const int g   = s >> 3, ss = s & 7;
    const int lb  = ss ^ (row & 7);          // logical block within 64-col group
    const int srcg = g & 15;                 // source 64-col group
    const bool lo = ((g >> 4) == LOSEG);

    const float* p = src + (size_t)row * 1024 + srcg * 64 + lb * 8;
    const float4 a = *(const float4*)p;
    const float4 bq = *(const float4*)(p + 4);
    const float xs[8] = {a.x, a.y, a.z, a.w, bq.x, bq.y, bq.z, bq.w};
    us8 o;
    #pragma unroll
    for (int e = 0; e < 8; ++e) {
        float x = xs[e];
        if (lo) { unsigned short h = f2b(x); x = x - b2f(h); }
        o[e] = f2b(x);
    }
    *(us8*)&dst[(size_t)row * 3072 + s * 8] = o;
}

// ---------------------------------------------------------------------------
// bf16 MFMA GEMM: C = A2 @ W2^T + bias, A2 [M][3072], W2 [1024][3072] (both
// pre-swizzled). 128x128 tile, BK=64, 4 waves x (64x64), double-buffered LDS,
// global_load_lds x16B, mfma_f32_16x16x32_bf16.
// SPLIT==1: C as [B][H][S][DK]; SPLIT==0: C as [M][1024].
// ---------------------------------------------------------------------------
template <int SPLIT>
__global__ __launch_bounds__(256) void mfma_gemm_kernel(
    const unsigned short* __restrict__ A2, const unsigned short* __restrict__ W2,
    const float* __restrict__ bias, float* __restrict__ C)
{
    constexpr int K3 = 3072;
    __shared__ bf16x8 Asl[2][1024];   // [buf][row*8+blk] : 128 rows x 8 x 16B
    __shared__ bf16x8 Bsl[2][1024];

    const int tid = threadIdx.x;
    const int wv = tid >> 6, ln = tid & 63;
    const int wm = wv >> 1, wn = wv & 1;
    const int bm = blockIdx.x * 128, bn = blockIdx.y * 128;
    const int x = ln & 15, y = ln >> 4;      // frag row & k-block

    f32x4 acc[4][4] = {};

    const unsigned short* Ab = A2 + (size_t)bm * K3;
    const unsigned short* Bb = W2 + (size_t)bn * K3;
    const int srow = ln >> 3;
    const int scol = (ln & 7) * 8;

    auto stage = [&](int bufi, int kt) {
        #pragma unroll
        for (int c = 0; c < 4; ++c) {
            const int rowb = wv * 32 + c * 8;
            const int r = rowb + srow;
            gl_lds16(Ab + (size_t)r * K3 + kt * 64 + scol,
                     (unsigned short*)&Asl[bufi][rowb << 3]);
            gl_lds16(Bb + (size_t)r * K3 + kt * 64 + scol,
                     (unsigned short*)&Bsl[bufi][rowb << 3]);
        }
    };

    stage(0, 0);
    asm volatile("s_waitcnt vmcnt(0)" ::: "memory");
    __syncthreads();

    int buf = 0;
    for (int kt = 0; kt < 48; ++kt) {
        if (kt < 47) stage(buf ^ 1, kt + 1);
        #pragma unroll
        for (int half = 0; half < 2; ++half) {
            bf16x8 af[4], bfr[4];
            #pragma unroll
            for (int mf = 0; mf < 4; ++mf) {
                const int r = wm * 64 + mf * 16 + x;
                af[mf] = Asl[buf][(r << 3) | ((half * 4 + y) ^ (r & 7))];
            }
            #pragma unroll
            for (int nf = 0; nf < 4; ++nf) {
                const int r = wn * 64 + nf * 16 + x;
                bfr[nf] = Bsl[buf][(r << 3) | ((half * 4 + y) ^ (r & 7))];
            }
            #pragma unroll
            for (int mf = 0; mf < 4; ++mf)
                #pragma unroll
                for (int nf = 0; nf < 4; ++nf)
                    acc[mf][nf] = __builtin_amdgcn_mfma_f32_16x16x32_bf16(
                        af[mf], bfr[nf], acc[mf][nf], 0, 0, 0);
        }
        asm volatile("s_waitcnt vmcnt(0)" ::: "memory");
        __syncthreads();
        buf ^= 1;
    }

    // epilogue: C/D layout col=lane&15, row=(lane>>4)*4+r  [m89-verified]
    #pragma unroll
    for (int nf = 0; nf < 4; ++nf) {
        const int n = bn + wn * 64 + nf * 16 + x;
        const float bv = bias[n];
        #pragma unroll
        for (int mf = 0; mf < 4; ++mf) {
            const int mbase = bm + wm * 64 + mf * 16 + y * 4;
            #pragma unroll
            for (int r = 0; r < 4; ++r) {
                const int m = mbase + r;
                const float v = acc[mf][nf][r] + bv;
                if (SPLIT) {
                    const int b = m >> 11, s = m & (SEQ - 1);
                    const int hh = n >> 6, dk = n & 63;
                    C[((size_t)((b * NUM_HEADS + hh) * SEQ + s)) * DK + dk] = v;
                } else {
                    C[(size_t)m * D_MODEL + n] = v;
                }
            }
        }
    }
}

// ---------------------------------------------------------------------------
// fp32 fallback GEMM (used only if ws_size too small for the MFMA path)
// ---------------------------------------------------------------------------
template <int SPLIT>
__global__ __launch_bounds__(256) void gemm_bias_kernel(
    const float* __restrict__ A, const float* __restrict__ W,
    const float* __restrict__ bias, float* __restrict__ C,
    int M, int N, int K)
{
    constexpr int TILE = 64, KT = 16;
    __shared__ float As[KT][TILE + 4];
    __shared__ float Ws[KT][TILE + 4];
    const int tid = threadIdx.x;
    const int tx = tid & 15, ty = tid >> 4;
    const int bm = blockIdx.x * TILE, bn = blockIdx.y * TILE;
    const int lrow = tid >> 2, lk4 = (tid & 3) << 2;
    float acc[4][4] = {{0.f}};
    for (int k0 = 0; k0 < K; k0 += KT) {
        const float4 a4 = *(const float4*)&A[(size_t)(bm + lrow) * K + k0 + lk4];
        const float4 w4 = *(const float4*)&W[(size_t)(bn + lrow) * K + k0 + lk4];
        __syncthreads();
        As[lk4 + 0][lrow] = a4.x; As[lk4 + 1][lrow] = a4.y;
        As[lk4 + 2][lrow] = a4.z; As[lk4 + 3][lrow] = a4.w;
        Ws[lk4 + 0][lrow] = w4.x; Ws[lk4 + 1][lrow] = w4.y;
        Ws[lk4 + 2][lrow] = w4.z; Ws[lk4 + 3][lrow] = w4.w;
        __syncthreads();
        #pragma unroll
        for (int kk = 0; kk < KT; ++kk) {
            const float4 av = *(const float4*)&As[kk][ty << 2];
            const float4 wv = *(const float4*)&Ws[kk][tx << 2];
            acc[0][0] += av.x * wv.x; acc[0][1] += av.x * wv.y; acc[0][2] += av.x * wv.z; acc[0][3] += av.x * wv.w;
            acc[1][0] += av.y * wv.x; acc[1][1] += av.y * wv.y; acc[1][2] += av.y * wv.z; acc[1][3] += av.y * wv.w;
            acc[2][0] += av.z * wv.x; acc[2][1] += av.z * wv.y; acc[2][2] += av.z * wv.z; acc[2][3] += av.z * wv.w;
            acc[3][0] += av.w * wv.x; acc[3][1] += av.w * wv.y; acc[3][2] += av.w * wv.z; acc[3][3] += av.w * wv.w;
        }
    }
    const float4 bb = *(const float4*)&bias[bn + (tx << 2)];
    #pragma unroll
    for (int i = 0; i < 4; ++i) {
        const int row = bm + (ty << 2) + i;
        float4 o;
        o.x = acc[i][0] + bb.x; o.y = acc[i][1] + bb.y;
        o.z = acc[i][2] + bb.z; o.w = acc[i][3] + bb.w;
        if (SPLIT) {
            const int b = row >> 11, s = row & (SEQ - 1), h = bn >> 6;
            *(float4*)&C[((size_t)((b * NUM_HEADS + h) * SEQ + s)) * DK + (tx << 2)] = o;
        } else {
            *(float4*)&C[(size_t)row * N + bn + (tx << 2)] = o;
        }
    }
}

// ---------------------------------------------------------------------------
// Flash attention, in-block key-split: 1024 blocks (4/CU), 4 waves/block.
// All waves own the SAME 64 q rows; the staged 64-key tile is split 16 keys
// per wave; 3-barrier LDS merge tree at the end reuses Ks/Vs as scratch.
// ---------------------------------------------------------------------------
__global__ __launch_bounds__(256, 4) void attn_kernel(
    const float* __restrict__ Q, const float* __restrict__ K,
    const float* __restrict__ V, const int* __restrict__ mask,
    float* __restrict__ CTX)
{
    const int qt = blockIdx.x;     // 0..31
    const int h  = blockIdx.y;
    const int b  = blockIdx.z;
    const int tid = threadIdx.x;
    const int wave = tid >> 6, lane = tid & 63;
    const int bh = b * NUM_HEADS + h;

    const float* Qb = Q + (size_t)bh * SEQ * DK;
    const float* Kb = K + (size_t)bh * SEQ * DK;
    const float* Vb = V + (size_t)bh * SEQ * DK;
    const int*   mb = mask + b * SEQ;

    __shared__ float Ks[64][68];
    __shared__ float Vs[64][68];

    const int row = qt * 64 + lane;
    float q[DK], ctx[DK];
    #pragma unroll
    for (int d4 = 0; d4 < 16; ++d4) {
        const float4 t = *(const float4*)&Qb[(size_t)row * DK + 4 * d4];
        q[4 * d4 + 0] = t.x; q[4 * d4 + 1] = t.y;
        q[4 * d4 + 2] = t.z; q[4 * d4 + 3] = t.w;
        ctx[4 * d4 + 0] = 0.f; ctx[4 * d4 + 1] = 0.f;
        ctx[4 * d4 + 2] = 0.f; ctx[4 * d4 + 3] = 0.f;
    }
    float m = -INFINITY, l = 0.f;
    const int c0 = wave * 16;

    for (int t = 0; t < SEQ / 64; ++t) {
        const int k0 = t * 64;
        const float* Kt = Kb + (size_t)k0 * DK;
        const float* Vt = Vb + (size_t)k0 * DK;
        __syncthreads();
        #pragma unroll
        for (int i = 0; i < 4; ++i) {
            const int f4 = i * 256 + tid;
            const int r = f4 >> 4, c = (f4 & 15) << 2;
            *(float4*)&Ks[r][c] = *(const float4*)&Kt[4 * f4];
            *(float4*)&Vs[r][c] = *(const float4*)&Vt[4 * f4];
        }
        __syncthreads();
        const unsigned long long mbits = __ballot(mb[k0 + lane] != 0);
        const unsigned bits = (unsigned)((mbits >> c0) & 0xFFFFULL);
        if (!bits) continue;

        float sc[16];
        #pragma unroll
        for (int j = 0; j < 16; ++j) {
            if (!((bits >> j) & 1u)) { sc[j] = -INFINITY; continue; }
            float a0 = 0.f, a1 = 0.f, a2 = 0.f, a3 = 0.f;
            #pragma unroll
            for (int d4 = 0; d4 < 16; ++d4) {
                const float4 kv = *(const float4*)&Ks[c0 + j][4 * d4];
                a0 += q[4 * d4 + 0] * kv.x;
                a1 += q[4 * d4 + 1] * kv.y;
                a2 += q[4 * d4 + 2] * kv.z;
                a3 += q[4 * d4 + 3] * kv.w;
            }
            sc[j] = ((a0 + a1) + (a2 + a3)) * 0.125f;   // 1/sqrt(64)
        }
        float cmax = sc[0];
        #pragma unroll
        for (int j = 1; j < 16; ++j) cmax = fmaxf(cmax, sc[j]);
        if (cmax > m) {
            const float scale = __expf(m - cmax);        // m=-inf -> 0
            l *= scale;
            #pragma unroll
            for (int d = 0; d < DK; ++d) ctx[d] *= scale;
            m = cmax;
        }
        #pragma unroll
        for (int j = 0; j < 16; ++j) {
            if (!((bits >> j) & 1u)) continue;
            const float p = __expf(sc[j] - m);
            l += p;
            #pragma unroll
            for (int d4 = 0; d4 < 16; ++d4) {
                const float4 vv = *(const float4*)&Vs[c0 + j][4 * d4];
                ctx[4 * d4 + 0] += p * vv.x;
                ctx[4 * d4 + 1] += p * vv.y;
                ctx[4 * d4 + 2] += p * vv.z;
                ctx[4 * d4 + 3] += p * vv.w;
            }
        }
    }

    // ---- in-block merge: (1,3) publish; (0,2) merge; 2 publishes; 0 merges
    __syncthreads();
    if (wave == 1 || wave == 3) {
        float* dl = (wave == 1) ? &Ks[lane][0] : &Vs[lane][0];
        #pragma unroll
        for (int d4 = 0; d4 < 16; ++d4)
            *(float4*)&dl[4 * d4] = make_float4(ctx[4*d4], ctx[4*d4+1], ctx[4*d4+2], ctx[4*d4+3]);
        dl[64] = m; dl[65] = l;
    }
    __syncthreads();
    if (wave == 0 || wave == 2) {
        const float* sl = (wave == 0) ? &Ks[lane][0] : &Vs[lane][0];
        const float m2 = sl[64], l2 = sl[65];
        const float M = fmaxf(m, m2);
        if (M > -INFINITY) {
            const float e1 = __expf(m - M), e2 = __expf(m2 - M);
            l = e1 * l + e2 * l2;
            #pragma unroll
            for (int d = 0; d < DK; ++d) ctx[d] = e1 * ctx[d] + e2 * sl[d];
            m = M;
        }
    }
    __syncthreads();
    if (wave == 2) {
        float* dl = &Ks[lane][0];
        #pragma unroll
        for (int d4 = 0; d4 < 16; ++d4)
            *(float4*)&dl[4 * d4] = make_float4(ctx[4*d4], ctx[4*d4+1], ctx[4*d4+2], ctx[4*d4+3]);
        dl[64] = m; dl[65] = l;
    }
    __syncthreads();
    if (wave == 0) {
        const float* sl = &Ks[lane][0];
        const float m2 = sl[64], l2 = sl[65];
        const float M = fmaxf(m, m2);
        if (M > -INFINITY) {
            const float e1 = __expf(m - M), e2 = __expf(m2 - M);
            l = e1 * l + e2 * l2;
            #pragma unroll
            for (int d = 0; d < DK; ++d) ctx[d] = e1 * ctx[d] + e2 * sl[d];
        }
        const float inv = (l > 0.f) ? (1.f / l) : 0.f;
        float* dst = CTX + ((size_t)(b * SEQ + row)) * D_MODEL + h * DK;
        #pragma unroll
        for (int d4 = 0; d4 < 16; ++d4) {
            float4 o;
            o.x = ctx[4 * d4 + 0] * inv; o.y = ctx[4 * d4 + 1] * inv;
            o.z = ctx[4 * d4 + 2] * inv; o.w = ctx[4 * d4 + 3] * inv;
            *(float4*)&dst[4 * d4] = o;
        }
    }
}

// ---------------------------------------------------------------------------
extern "C" void kernel_launch(void* const* d_in, const int* in_sizes, int n_in,
                              void* d_out, int out_size, void* d_ws, size_t ws_size,
                              hipStream_t stream)
{
    const float* query = (const float*)d_in[0];
    const float* key_  = (const float*)d_in[1];
    const float* value = (const float*)d_in[2];
    const int*   mask  = (const int*)d_in[3];
    const float* Wq = (const float*)d_in[4];
    const float* bq = (const float*)d_in[5];
    const float* Wk = (const float*)d_in[6];
    const float* bk = (const float*)d_in[7];
    const float* Wv = (const float*)d_in[8];
    const float* bv = (const float*)d_in[9];
    const float* Wo = (const float*)d_in[10];
    const float* bo = (const float*)d_in[11];
    float* out = (float*)d_out;

    const int M = BATCH * SEQ;                 // 4096
    const size_t PER_B  = (size_t)M * D_MODEL * 4;       // 16 MB fp32 activation
    const size_t ACT2_B = (size_t)M * 3072 * 2;          // 24 MB bf16 hilo act
    const size_t W2_B   = (size_t)D_MODEL * 3072 * 2;    // 6 MB bf16 hilo weight

    char* base = (char*)d_ws;
    float* q_ws = (float*)(base + 0 * PER_B);
    float* k_ws = (float*)(base + 1 * PER_B);
    float* v_ws = (float*)(base + 2 * PER_B);
    float* c_ws = (float*)(base + 3 * PER_B);
    unsigned short* act2 = (unsigned short*)(base + 4 * PER_B);
    unsigned short* w2q = (unsigned short*)(base + 4 * PER_B + ACT2_B);
    unsigned short* w2k = (unsigned short*)((char*)w2q + W2_B);
    unsigned short* w2v = (unsigned short*)((char*)w2k + W2_B);
    unsigned short* w2o = (unsigned short*)((char*)w2v + W2_B);
    const size_t need = 4 * PER_B + ACT2_B + 4 * W2_B;   // 112 MB

    dim3 agrid(SEQ / 64, NUM_HEADS, BATCH);              // 32,16,2 = 1024 blocks

    if (ws_size >= need) {
        const int wblk = (D_MODEL * 384 + 255) / 256;    // 1536
        const int ablk = (M * 384 + 255) / 256;          // 6144
        conv_hilo_kernel<2><<<wblk, 256, 0, stream>>>(Wq, w2q, D_MODEL);
        conv_hilo_kernel<2><<<wblk, 256, 0, stream>>>(Wk, w2k, D_MODEL);
        conv_hilo_kernel<2><<<wblk, 256, 0, stream>>>(Wv, w2v, D_MODEL);
        conv_hilo_kernel<2><<<wblk, 256, 0, stream>>>(Wo, w2o, D_MODEL);

        dim3 ggrid(M / 128, D_MODEL / 128);              // 32,8
        conv_hilo_kernel<1><<<ablk, 256, 0, stream>>>(query, act2, M);
        mfma_gemm_kernel<1><<<ggrid, 256, 0, stream>>>(act2, w2q, bq, q_ws);
        conv_hilo_kernel<1><<<ablk, 256, 0, stream>>>(key_, act2, M);
        mfma_gemm_kernel<1><<<ggrid, 256, 0, stream>>>(act2, w2k, bk, k_ws);
        conv_hilo_kernel<1><<<ablk, 256, 0, stream>>>(value, act2, M);
        mfma_gemm_kernel<1><<<ggrid, 256, 0, stream>>>(act2, w2v, bv, v_ws);

        attn_kernel<<<agrid, 256, 0, stream>>>(q_ws, k_ws, v_ws, mask, c_ws);

        conv_hilo_kernel<1><<<ablk, 256, 0, stream>>>(c_ws, act2, M);
        mfma_gemm_kernel<0><<<ggrid, 256, 0, stream>>>(act2, w2o, bo, out);
    } else {
        dim3 ggrid(M / 64, D_MODEL / 64);
        gemm_bias_kernel<1><<<ggrid, 256, 0, stream>>>(query, Wq, bq, q_ws, M, D_MODEL, D_MODEL);
        gemm_bias_kernel<1><<<ggrid, 256, 0, stream>>>(key_,  Wk, bk, k_ws, M, D_MODEL, D_MODEL);
        gemm_bias_kernel<1><<<ggrid, 256, 0, stream>>>(value, Wv, bv, v_ws, M, D_MODEL, D_MODEL);
        attn_kernel<<<agrid, 256, 0, stream>>>(q_ws, k_ws, v_ws, mask, c_ws);
        gemm_bias_kernel<0><<<ggrid, 256, 0, stream>>>(c_ws, Wo, bo, out, M, D_MODEL, D_MODEL);
    }
}

// Round 6
// 389.231 us; speedup vs baseline: 5.6396x; 5.6396x over previous
//
#include <hip/hip_runtime.h>
#include <math.h>

#define D_MODEL 1024
#define NUM_HEADS 16
#define DK 64
#define BATCH 2
#define SEQ 2048

using f32x4  = __attribute__((ext_vector_type(4))) float;
using bf16x8 = __attribute__((ext_vector_type(8))) short;
using us8    = __attribute__((ext_vector_type(8))) unsigned short;

__device__ __forceinline__ unsigned short f2b(float x) {  // fp32 -> bf16 RNE
    unsigned u = __float_as_uint(x);
    return (unsigned short)((u + 0x7FFF + ((u >> 16) & 1)) >> 16);
}
__device__ __forceinline__ float b2f(unsigned short h) {
    return __uint_as_float(((unsigned)h) << 16);
}
__device__ __forceinline__ void gl_lds16(const unsigned short* g, unsigned short* l) {
    __builtin_amdgcn_global_load_lds(
        (const __attribute__((address_space(1))) void*)g,
        (__attribute__((address_space(3))) void*)l, 16, 0, 0);
}

// ---------------------------------------------------------------------------
// fp32 [rows][1024] -> bf16 [rows][3072] along K (GEMM operand), row-XOR
// swizzle baked in. LOSEG: which K-third carries the lo residual.
//   activations LOSEG=1 -> [hi | lo | hi],  weights LOSEG=2 -> [hi | hi | lo]
// ---------------------------------------------------------------------------
template <int LOSEG>
__global__ __launch_bounds__(256) void conv_hilo_kernel(
    const float* __restrict__ src, unsigned short* __restrict__ dst, int rows)
{
    const int id = blockIdx.x * 256 + threadIdx.x;
    if (id >= rows * 384) return;
    const int row = id / 384;
    const int s   = id - row * 384;
    const int g   = s >> 3, ss = s & 7;
    const int lb  = ss ^ (row & 7);
    const int srcg = g & 15;
    const bool lo = ((g >> 4) == LOSEG);

    const float* p = src + (size_t)row * 1024 + srcg * 64 + lb * 8;
    const float4 a = *(const float4*)p;
    const float4 bq = *(const float4*)(p + 4);
    const float xs[8] = {a.x, a.y, a.z, a.w, bq.x, bq.y, bq.z, bq.w};
    us8 o;
    #pragma unroll
    for (int e = 0; e < 8; ++e) {
        float x = xs[e];
        if (lo) { unsigned short h = f2b(x); x = x - b2f(h); }
        o[e] = f2b(x);
    }
    *(us8*)&dst[(size_t)row * 3072 + s * 8] = o;
}

// ---------------------------------------------------------------------------
// bf16 MFMA GEMM: C = A2 @ W2^T + bias, K=3072 hi/lo. MODE selects epilogue:
//  0: fp32 [M][1024]            1: fp32 split [b][h][s][dk]
//  2: K2  bf16 [bh][key][128] = hi(64,swz) | lo(64,swz)   (attn K operand)
//  3: VT2 bf16 [bh][d][2048], key-block swizzle per 64-tile (attn V^T operand)
// ---------------------------------------------------------------------------
template <int MODE>
__global__ __launch_bounds__(256) void mfma_gemm_kernel(
    const unsigned short* __restrict__ A2, const unsigned short* __restrict__ W2,
    const float* __restrict__ bias, float* __restrict__ Cf,
    unsigned short* __restrict__ Cb)
{
    constexpr int K3 = 3072;
    __shared__ bf16x8 Asl[2][1024];
    __shared__ bf16x8 Bsl[2][1024];

    const int tid = threadIdx.x;
    const int wv = tid >> 6, ln = tid & 63;
    const int wm = wv >> 1, wn = wv & 1;
    const int bm = blockIdx.x * 128, bn = blockIdx.y * 128;
    const int x = ln & 15, y = ln >> 4;

    f32x4 acc[4][4] = {};

    const unsigned short* Ab = A2 + (size_t)bm * K3;
    const unsigned short* Bb = W2 + (size_t)bn * K3;
    const int srow = ln >> 3;
    const int scol = (ln & 7) * 8;

    auto stage = [&](int bufi, int kt) {
        #pragma unroll
        for (int c = 0; c < 4; ++c) {
            const int rowb = wv * 32 + c * 8;
            const int r = rowb + srow;
            gl_lds16(Ab + (size_t)r * K3 + kt * 64 + scol,
                     (unsigned short*)&Asl[bufi][rowb << 3]);
            gl_lds16(Bb + (size_t)r * K3 + kt * 64 + scol,
                     (unsigned short*)&Bsl[bufi][rowb << 3]);
        }
    };

    stage(0, 0);
    asm volatile("s_waitcnt vmcnt(0)" ::: "memory");
    __syncthreads();

    int buf = 0;
    for (int kt = 0; kt < 48; ++kt) {
        if (kt < 47) stage(buf ^ 1, kt + 1);
        #pragma unroll
        for (int half = 0; half < 2; ++half) {
            bf16x8 af[4], bfr[4];
            #pragma unroll
            for (int mf = 0; mf < 4; ++mf) {
                const int r = wm * 64 + mf * 16 + x;
                af[mf] = Asl[buf][(r << 3) | ((half * 4 + y) ^ (r & 7))];
            }
            #pragma unroll
            for (int nf = 0; nf < 4; ++nf) {
                const int r = wn * 64 + nf * 16 + x;
                bfr[nf] = Bsl[buf][(r << 3) | ((half * 4 + y) ^ (r & 7))];
            }
            #pragma unroll
            for (int mf = 0; mf < 4; ++mf)
                #pragma unroll
                for (int nf = 0; nf < 4; ++nf)
                    acc[mf][nf] = __builtin_amdgcn_mfma_f32_16x16x32_bf16(
                        af[mf], bfr[nf], acc[mf][nf], 0, 0, 0);
        }
        asm volatile("s_waitcnt vmcnt(0)" ::: "memory");
        __syncthreads();
        buf ^= 1;
    }

    // epilogue: C/D layout col=lane&15 (n), row=(lane>>4)*4+r (m)
    #pragma unroll
    for (int nf = 0; nf < 4; ++nf) {
        const int n = bn + wn * 64 + nf * 16 + x;
        const float bv = bias[n];
        #pragma unroll
        for (int mf = 0; mf < 4; ++mf) {
            const int mbase = bm + wm * 64 + mf * 16 + y * 4;
            #pragma unroll
            for (int r = 0; r < 4; ++r) {
                const int m = mbase + r;
                const float v = acc[mf][nf][r] + bv;
                const int b = m >> 11, s = m & (SEQ - 1);
                const int hh = n >> 6, dd = n & 63;
                if (MODE == 0) {
                    Cf[(size_t)m * D_MODEL + n] = v;
                } else if (MODE == 1) {
                    Cf[((size_t)((b * NUM_HEADS + hh) * SEQ + s)) * DK + dd] = v;
                } else if (MODE == 2) {
                    // K2: row = key (= s), cols: hi | lo, 8-elem blocks XOR key&7
                    const unsigned short hi = f2b(v);
                    const unsigned short lo = f2b(v - b2f(hi));
                    const int blk = (dd >> 3) ^ (s & 7), i = dd & 7;
                    unsigned short* kp = Cb +
                        ((size_t)((b * NUM_HEADS + hh) * SEQ + s)) * 128;
                    kp[blk * 8 + i] = hi;
                    kp[64 + blk * 8 + i] = lo;
                } else {
                    // VT2: [bh][d][2048], key-block swizzle by d&7 within 64-tile
                    const int tile = s >> 6, w = s & 63;
                    const int blk = (w >> 3) ^ (dd & 7), i = w & 7;
                    Cb[((size_t)((b * NUM_HEADS + hh) * DK + dd)) * SEQ +
                       tile * 64 + blk * 8 + i] = f2b(v);
                }
            }
        }
    }
}

// ---------------------------------------------------------------------------
// MFMA flash attention. Block = 4 waves, one (b,h) x 64-q-row tile.
// Wave owns 16 q rows. Per 64-key tile: stage Khi/Klo/V^T (swizzled) via
// global_load_lds; S^T = mfma(K,Q) hi/lo (fp32-accurate scores); online
// softmax per-lane (col = q = lane&15, 2 shfl_xor reduces); P->bf16 through
// per-wave swizzled LDS; ctx^T += mfma(V^T, P). XCD-chunked block swizzle.
// ---------------------------------------------------------------------------
__global__ __launch_bounds__(256, 3) void attn_mfma_kernel(
    const float* __restrict__ Q, const unsigned short* __restrict__ K2,
    const unsigned short* __restrict__ VT2, const int* __restrict__ mask,
    float* __restrict__ CTX)
{
    __shared__ __align__(16) unsigned short SM[16384];   // 32 KB
    unsigned short* Khi = SM;            // [64 key][64 dk]
    unsigned short* Klo = SM + 4096;
    unsigned short* VTs = SM + 8192;     // [64 d][64 key]

    const int tid = threadIdx.x;
    const int wave = tid >> 6, lane = tid & 63;
    const int lo4 = lane & 15, hi4 = lane >> 4;
    unsigned short* Pw = SM + 12288 + wave * 1024;  // [16 q][64 key] bf16

    const int orig = blockIdx.x;
    const int swz = (orig & 7) * 128 + (orig >> 3);  // 1024%8==0: bijective
    const int bh = swz >> 5, qblk = swz & 31;
    const int b = bh >> 4, h = bh & 15;

    const float* Qb = Q + (size_t)bh * SEQ * DK;
    const unsigned short* Kb = K2 + (size_t)bh * SEQ * 128;
    const unsigned short* Vb = VT2 + (size_t)bh * DK * SEQ;
    const int* mb = mask + b * SEQ;

    // Q fragments (hi/lo): row = q = lane&15, k = (lane>>4)*8+i per 32-chunk
    const int qr = qblk * 64 + wave * 16 + lo4;
    bf16x8 qhi[2], qlo[2];
    #pragma unroll
    for (int c = 0; c < 2; ++c) {
        const float* qp = &Qb[(size_t)qr * DK + c * 32 + hi4 * 8];
        const float4 x0 = *(const float4*)qp;
        const float4 x1 = *(const float4*)(qp + 4);
        const float xs[8] = {x0.x, x0.y, x0.z, x0.w, x1.x, x1.y, x1.z, x1.w};
        #pragma unroll
        for (int i = 0; i < 8; ++i) {
            const unsigned short hh = f2b(xs[i]);
            qhi[c][i] = (short)hh;
            qlo[c][i] = (short)f2b(xs[i] - b2f(hh));
        }
    }

    f32x4 ctx[4] = {};   // ctx^T frags: [dt], row d = dt*16+hi4*4+r, col q=lo4
    float m = -INFINITY, l = 0.f;

    for (int t = 0; t < SEQ / 64; ++t) {
        const int k0 = t * 64;
        __syncthreads();
        // stage 24 KB: Khi(512 x16B) | Klo(512) | VT(512); 6 x 256 lanes
        #pragma unroll
        for (int j = 0; j < 6; ++j) {
            const int g = j * 256 + wave * 64;   // wave-uniform
            const int gi = g + lane;
            const unsigned short* src;
            if (gi < 512) {
                src = Kb + (size_t)(k0 + (gi >> 3)) * 128 + (gi & 7) * 8;
            } else if (gi < 1024) {
                const int g2 = gi - 512;
                src = Kb + (size_t)(k0 + (g2 >> 3)) * 128 + 64 + (g2 & 7) * 8;
            } else {
                const int g3 = gi - 1024;
                src = Vb + (size_t)(g3 >> 3) * SEQ + k0 + (g3 & 7) * 8;
            }
            gl_lds16(src, SM + (size_t)g * 8);
        }
        asm volatile("s_waitcnt vmcnt(0)" ::: "memory");
        __syncthreads();

        const unsigned long long mbits = __ballot(mb[k0 + lane] != 0);
        const unsigned long long sh = mbits >> (hi4 * 4);
        const unsigned nib[4] = {
            (unsigned)sh & 15u, (unsigned)(sh >> 16) & 15u,
            (unsigned)(sh >> 32) & 15u, (unsigned)(sh >> 48) & 15u};

        // S^T = K . Q^T : rows = key, cols = q
        f32x4 sc[4];
        #pragma unroll
        for (int kt = 0; kt < 4; ++kt) {
            f32x4 s = {0.f, 0.f, 0.f, 0.f};
            const int row = kt * 16 + lo4;
            const int rx = row & 7;
            #pragma unroll
            for (int c = 0; c < 2; ++c) {
                const int blk = ((c * 4 + hi4) ^ rx) * 8;
                const bf16x8 kh = *(bf16x8*)&Khi[row * 64 + blk];
                const bf16x8 kl = *(bf16x8*)&Klo[row * 64 + blk];
                s = __builtin_amdgcn_mfma_f32_16x16x32_bf16(kh, qhi[c], s, 0, 0, 0);
                s = __builtin_amdgcn_mfma_f32_16x16x32_bf16(kl, qhi[c], s, 0, 0, 0);
                s = __builtin_amdgcn_mfma_f32_16x16x32_bf16(kh, qlo[c], s, 0, 0, 0);
            }
            sc[kt] = s;
        }

        // mask + scale + row-max (keys of this lane: kt*16 + hi4*4 + r)
        float cmax = -1e30f;
        #pragma unroll
        for (int kt = 0; kt < 4; ++kt) {
            #pragma unroll
            for (int r = 0; r < 4; ++r) {
                float sv = sc[kt][r] * 0.125f;
                sv = ((nib[kt] >> r) & 1u) ? sv : -1e30f;
                sc[kt][r] = sv;
                cmax = fmaxf(cmax, sv);
            }
        }
        cmax = fmaxf(cmax, __shfl_xor(cmax, 16));
        cmax = fmaxf(cmax, __shfl_xor(cmax, 32));

        const float mnew = fmaxf(m, cmax);
        const float e1 = __expf(m - mnew);   // m=-inf only pre-first-tile -> 0
        m = mnew;

        float ps = 0.f;
        #pragma unroll
        for (int kt = 0; kt < 4; ++kt) {
            float pv0 = ((nib[kt] >> 0) & 1u) ? __expf(sc[kt][0] - mnew) : 0.f;
            float pv1 = ((nib[kt] >> 1) & 1u) ? __expf(sc[kt][1] - mnew) : 0.f;
            float pv2 = ((nib[kt] >> 2) & 1u) ? __expf(sc[kt][2] - mnew) : 0.f;
            float pv3 = ((nib[kt] >> 3) & 1u) ? __expf(sc[kt][3] - mnew) : 0.f;
            ps += (pv0 + pv1) + (pv2 + pv3);
            const unsigned w0 = (unsigned)f2b(pv0) | ((unsigned)f2b(pv1) << 16);
            const unsigned w1 = (unsigned)f2b(pv2) | ((unsigned)f2b(pv3) << 16);
            const int blk16 = (kt * 2 + (hi4 >> 1)) ^ (lo4 & 7);
            unsigned* dst = (unsigned*)&Pw[lo4 * 64 + blk16 * 8 + (hi4 & 1) * 4];
            dst[0] = w0; dst[1] = w1;
        }
        ps += __shfl_xor(ps, 16);
        ps += __shfl_xor(ps, 32);
        l = l * e1 + ps;

        #pragma unroll
        for (int dt = 0; dt < 4; ++dt)
            #pragma unroll
            for (int r = 0; r < 4; ++r) ctx[dt][r] *= e1;

        // ctx^T += V^T . P^T  (same-wave LDS RAW: DS pipe is in-order)
        #pragma unroll
        for (int c = 0; c < 2; ++c) {
            const bf16x8 pf =
                *(bf16x8*)&Pw[lo4 * 64 + (((c * 4 + hi4) ^ (lo4 & 7)) * 8)];
            #pragma unroll
            for (int dt = 0; dt < 4; ++dt) {
                const int row = dt * 16 + lo4;
                const bf16x8 vf =
                    *(bf16x8*)&VTs[row * 64 + (((c * 4 + hi4) ^ (row & 7)) * 8)];
                ctx[dt] = __builtin_amdgcn_mfma_f32_16x16x32_bf16(vf, pf, ctx[dt], 0, 0, 0);
            }
        }
    }

    // epilogue: normalize, transpose via LDS, coalesced store
    __syncthreads();
    const float inv = (l > 0.f) ? (1.f / l) : 0.f;   // l==0: fully masked -> 0
    float* OutL = (float*)SM;                        // [64 q][64 d] fp32, 16 KB
    #pragma unroll
    for (int dt = 0; dt < 4; ++dt)
        #pragma unroll
        for (int r = 0; r < 4; ++r)
            OutL[(wave * 16 + lo4) * 64 + dt * 16 + hi4 * 4 + r] = ctx[dt][r] * inv;
    __syncthreads();
    {
        const int row = tid >> 2, cb = (tid & 3) * 16;
        float* dst = CTX + ((size_t)(b * SEQ + qblk * 64 + row)) * D_MODEL
                         + h * DK + cb;
        #pragma unroll
        for (int u = 0; u < 4; ++u)
            *(float4*)&dst[u * 4] = *(float4*)&OutL[row * 64 + cb + u * 4];
    }
}

// ---------------------------------------------------------------------------
// fp32 fallback path (only if ws too small): simple GEMM + r3-proven attention
// ---------------------------------------------------------------------------
template <int SPLIT>
__global__ __launch_bounds__(256) void gemm_bias_kernel(
    const float* __restrict__ A, const float* __restrict__ W,
    const float* __restrict__ bias, float* __restrict__ C,
    int M, int N, int K)
{
    constexpr int TILE = 64, KT = 16;
    __shared__ float As[KT][TILE + 4];
    __shared__ float Ws[KT][TILE + 4];
    const int tid = threadIdx.x;
    const int tx = tid & 15, ty = tid >> 4;
    const int bm = blockIdx.x * TILE, bn = blockIdx.y * TILE;
    const int lrow = tid >> 2, lk4 = (tid & 3) << 2;
    float acc[4][4] = {{0.f}};
    for (int k0 = 0; k0 < K; k0 += KT) {
        const float4 a4 = *(const float4*)&A[(size_t)(bm + lrow) * K + k0 + lk4];
        const float4 w4 = *(const float4*)&W[(size_t)(bn + lrow) * K + k0 + lk4];
        __syncthreads();
        As[lk4 + 0][lrow] = a4.x; As[lk4 + 1][lrow] = a4.y;
        As[lk4 + 2][lrow] = a4.z; As[lk4 + 3][lrow] = a4.w;
        Ws[lk4 + 0][lrow] = w4.x; Ws[lk4 + 1][lrow] = w4.y;
        Ws[lk4 + 2][lrow] = w4.z; Ws[lk4 + 3][lrow] = w4.w;
        __syncthreads();
        #pragma unroll
        for (int kk = 0; kk < KT; ++kk) {
            const float4 av = *(const float4*)&As[kk][ty << 2];
            const float4 wv = *(const float4*)&Ws[kk][tx << 2];
            acc[0][0] += av.x * wv.x; acc[0][1] += av.x * wv.y; acc[0][2] += av.x * wv.z; acc[0][3] += av.x * wv.w;
            acc[1][0] += av.y * wv.x; acc[1][1] += av.y * wv.y; acc[1][2] += av.y * wv.z; acc[1][3] += av.y * wv.w;
            acc[2][0] += av.z * wv.x; acc[2][1] += av.z * wv.y; acc[2][2] += av.z * wv.z; acc[2][3] += av.z * wv.w;
            acc[3][0] += av.w * wv.x; acc[3][1] += av.w * wv.y; acc[3][2] += av.w * wv.z; acc[3][3] += av.w * wv.w;
        }
    }
    const float4 bb = *(const float4*)&bias[bn + (tx << 2)];
    #pragma unroll
    for (int i = 0; i < 4; ++i) {
        const int row = bm + (ty << 2) + i;
        float4 o;
        o.x = acc[i][0] + bb.x; o.y = acc[i][1] + bb.y;
        o.z = acc[i][2] + bb.z; o.w = acc[i][3] + bb.w;
        if (SPLIT) {
            const int b = row >> 11, s = row & (SEQ - 1), hh = bn >> 6;
            *(float4*)&C[((size_t)((b * NUM_HEADS + hh) * SEQ + s)) * DK + (tx << 2)] = o;
        } else {
            *(float4*)&C[(size_t)row * N + bn + (tx << 2)] = o;
        }
    }
}

__global__ __launch_bounds__(256, 2) void attn_fp32_kernel(
    const float* __restrict__ Q, const float* __restrict__ K,
    const float* __restrict__ V, const int* __restrict__ mask,
    float* __restrict__ OUT)
{
    const int qb = blockIdx.x, h = blockIdx.y, b = blockIdx.z;
    const int wave = threadIdx.x >> 6, lane = threadIdx.x & 63;
    const int tid = threadIdx.x;
    const int bh = b * NUM_HEADS + h;
    const float* Qb = Q + (size_t)bh * SEQ * DK;
    const float* Kb = K + (size_t)bh * SEQ * DK;
    const float* Vb = V + (size_t)bh * SEQ * DK;
    const int* mb = mask + b * SEQ;
    __shared__ float Ks[64][68];
    __shared__ float Vs[64][68];
    const int row = qb * 256 + wave * 64 + lane;
    float q[DK], ctx[DK];
    #pragma unroll
    for (int d4 = 0; d4 < 16; ++d4) {
        const float4 t = *(const float4*)&Qb[(size_t)row * DK + 4 * d4];
        q[4*d4] = t.x; q[4*d4+1] = t.y; q[4*d4+2] = t.z; q[4*d4+3] = t.w;
        ctx[4*d4] = 0.f; ctx[4*d4+1] = 0.f; ctx[4*d4+2] = 0.f; ctx[4*d4+3] = 0.f;
    }
    float m = -INFINITY, l = 0.f;
    for (int t = 0; t < SEQ / 64; ++t) {
        const int k0 = t * 64;
        const float* Kt = Kb + (size_t)k0 * DK;
        const float* Vt = Vb + (size_t)k0 * DK;
        __syncthreads();
        #pragma unroll
        for (int i = 0; i < 4; ++i) {
            const int f4 = i * 256 + tid;
            const int r = f4 >> 4, c = (f4 & 15) << 2;
            *(float4*)&Ks[r][c] = *(const float4*)&Kt[4 * f4];
            *(float4*)&Vs[r][c] = *(const float4*)&Vt[4 * f4];
        }
        __syncthreads();
        const unsigned long long mbits = __ballot(mb[k0 + lane] != 0);
        if (mbits == 0ULL) continue;
        for (int c0 = 0; c0 < 64; c0 += 16) {
            const unsigned bits = (unsigned)((mbits >> c0) & 0xFFFFULL);
            if (!bits) continue;
            float sc[16];
            #pragma unroll
            for (int j = 0; j < 16; ++j) {
                if (!((bits >> j) & 1u)) { sc[j] = -INFINITY; continue; }
                float a0 = 0.f, a1 = 0.f, a2 = 0.f, a3 = 0.f;
                #pragma unroll
                for (int d4 = 0; d4 < 16; ++d4) {
                    const float4 kv = *(const float4*)&Ks[c0 + j][4 * d4];
                    a0 += q[4*d4] * kv.x; a1 += q[4*d4+1] * kv.y;
                    a2 += q[4*d4+2] * kv.z; a3 += q[4*d4+3] * kv.w;
                }
                sc[j] = ((a0 + a1) + (a2 + a3)) * 0.125f;
            }
            float cmax = sc[0];
            #pragma unroll
            for (int j = 1; j < 16; ++j) cmax = fmaxf(cmax, sc[j]);
            if (cmax > m) {
                const float scale = __expf(m - cmax);
                l *= scale;
                #pragma unroll
                for (int d = 0; d < DK; ++d) ctx[d] *= scale;
                m = cmax;
            }
            #pragma unroll
            for (int j = 0; j < 16; ++j) {
                if (!((bits >> j) & 1u)) continue;
                const float p = __expf(sc[j] - m);
                l += p;
                #pragma unroll
                for (int d4 = 0; d4 < 16; ++d4) {
                    const float4 vv = *(const float4*)&Vs[c0 + j][4 * d4];
                    ctx[4*d4] += p * vv.x; ctx[4*d4+1] += p * vv.y;
                    ctx[4*d4+2] += p * vv.z; ctx[4*d4+3] += p * vv.w;
                }
            }
        }
    }
    const float inv = (l > 0.f) ? (1.f / l) : 0.f;
    float* dst = OUT + ((size_t)(b * SEQ + row)) * D_MODEL + h * DK;
    #pragma unroll
    for (int d4 = 0; d4 < 16; ++d4) {
        float4 o;
        o.x = ctx[4*d4] * inv; o.y = ctx[4*d4+1] * inv;
        o.z = ctx[4*d4+2] * inv; o.w = ctx[4*d4+3] * inv;
        *(float4*)&dst[4 * d4] = o;
    }
}

// ---------------------------------------------------------------------------
extern "C" void kernel_launch(void* const* d_in, const int* in_sizes, int n_in,
                              void* d_out, int out_size, void* d_ws, size_t ws_size,
                              hipStream_t stream)
{
    const float* query = (const float*)d_in[0];
    const float* key_  = (const float*)d_in[1];
    const float* value = (const float*)d_in[2];
    const int*   mask  = (const int*)d_in[3];
    const float* Wq = (const float*)d_in[4];
    const float* bq = (const float*)d_in[5];
    const float* Wk = (const float*)d_in[6];
    const float* bk = (const float*)d_in[7];
    const float* Wv = (const float*)d_in[8];
    const float* bv = (const float*)d_in[9];
    const float* Wo = (const float*)d_in[10];
    const float* bo = (const float*)d_in[11];
    float* out = (float*)d_out;

    const int M = BATCH * SEQ;                            // 4096
    const size_t PER_B  = (size_t)M * D_MODEL * 4;        // 16 MB
    const size_t ACT2_B = (size_t)M * 3072 * 2;           // 24 MB
    const size_t W2_B   = (size_t)D_MODEL * 3072 * 2;     // 6.3 MB
    const size_t K2_B   = (size_t)32 * SEQ * 128 * 2;     // 16.8 MB
    const size_t VT2_B  = (size_t)32 * DK * SEQ * 2;      // 8.4 MB

    char* base = (char*)d_ws;
    float* q_ws = (float*)(base);
    float* c_ws = (float*)(base + PER_B);
    unsigned short* act2 = (unsigned short*)(base + 2 * PER_B);
    unsigned short* w2q = (unsigned short*)(base + 2 * PER_B + ACT2_B);
    unsigned short* w2k = (unsigned short*)((char*)w2q + W2_B);
    unsigned short* w2v = (unsigned short*)((char*)w2k + W2_B);
    unsigned short* w2o = (unsigned short*)((char*)w2v + W2_B);
    unsigned short* k2  = (unsigned short*)((char*)w2o + W2_B);
    unsigned short* vt2 = (unsigned short*)((char*)k2 + K2_B);
    const size_t need = 2 * PER_B + ACT2_B + 4 * W2_B + K2_B + VT2_B; // ~109 MB

    if (ws_size >= need) {
        const int wblk = (D_MODEL * 384 + 255) / 256;
        const int ablk = (M * 384 + 255) / 256;
        conv_hilo_kernel<2><<<wblk, 256, 0, stream>>>(Wq, w2q, D_MODEL);
        conv_hilo_kernel<2><<<wblk, 256, 0, stream>>>(Wk, w2k, D_MODEL);
        conv_hilo_kernel<2><<<wblk, 256, 0, stream>>>(Wv, w2v, D_MODEL);
        conv_hilo_kernel<2><<<wblk, 256, 0, stream>>>(Wo, w2o, D_MODEL);

        dim3 ggrid(M / 128, D_MODEL / 128);
        conv_hilo_kernel<1><<<ablk, 256, 0, stream>>>(query, act2, M);
        mfma_gemm_kernel<1><<<ggrid, 256, 0, stream>>>(act2, w2q, bq, q_ws, nullptr);
        conv_hilo_kernel<1><<<ablk, 256, 0, stream>>>(key_, act2, M);
        mfma_gemm_kernel<2><<<ggrid, 256, 0, stream>>>(act2, w2k, bk, nullptr, k2);
        conv_hilo_kernel<1><<<ablk, 256, 0, stream>>>(value, act2, M);
        mfma_gemm_kernel<3><<<ggrid, 256, 0, stream>>>(act2, w2v, bv, nullptr, vt2);

        attn_mfma_kernel<<<1024, 256, 0, stream>>>(q_ws, k2, vt2, mask, c_ws);

        conv_hilo_kernel<1><<<ablk, 256, 0, stream>>>(c_ws, act2, M);
        mfma_gemm_kernel<0><<<ggrid, 256, 0, stream>>>(act2, w2o, bo, out, nullptr);
    } else {
        float* k_ws = (float*)(base + 2 * PER_B);
        float* v_ws = (float*)(base + 3 * PER_B);
        dim3 ggrid(M / 64, D_MODEL / 64);
        gemm_bias_kernel<1><<<ggrid, 256, 0, stream>>>(query, Wq, bq, q_ws, M, D_MODEL, D_MODEL);
        gemm_bias_kernel<1><<<ggrid, 256, 0, stream>>>(key_,  Wk, bk, k_ws, M, D_MODEL, D_MODEL);
        gemm_bias_kernel<1><<<ggrid, 256, 0, stream>>>(value, Wv, bv, v_ws, M, D_MODEL, D_MODEL);
        dim3 agrid(SEQ / 256, NUM_HEADS, BATCH);
        attn_fp32_kernel<<<agrid, 256, 0, stream>>>(q_ws, k_ws, v_ws, mask, c_ws);
        gemm_bias_kernel<0><<<ggrid, 256, 0, stream>>>(c_ws, Wo, bo, out, M, D_MODEL, D_MODEL);
    }
}

// Round 7
// 311.411 us; speedup vs baseline: 7.0489x; 1.2499x over previous
//
#include <hip/hip_runtime.h>
#include <math.h>

#define D_MODEL 1024
#define NUM_HEADS 16
#define DK 64
#define BATCH 2
#define SEQ 2048

using f32x4  = __attribute__((ext_vector_type(4))) float;
using bf16x8 = __attribute__((ext_vector_type(8))) short;
using us8    = __attribute__((ext_vector_type(8))) unsigned short;

__device__ __forceinline__ unsigned short f2b(float x) {  // fp32 -> bf16 RNE
    unsigned u = __float_as_uint(x);
    return (unsigned short)((u + 0x7FFF + ((u >> 16) & 1)) >> 16);
}
__device__ __forceinline__ float b2f(unsigned short h) {
    return __uint_as_float(((unsigned)h) << 16);
}
__device__ __forceinline__ void gl_lds16(const unsigned short* g, unsigned short* l) {
    __builtin_amdgcn_global_load_lds(
        (const __attribute__((address_space(1))) void*)g,
        (__attribute__((address_space(3))) void*)l, 16, 0, 0);
}

// ---------------------------------------------------------------------------
// Per-batch prefix scan of mask: pos[b][s] = #valid keys before s, nc[b]=count
// ---------------------------------------------------------------------------
__global__ __launch_bounds__(256) void mask_scan_kernel(
    const int* __restrict__ mask, int* __restrict__ pos, int* __restrict__ nc)
{
    const int b = blockIdx.x;
    const int tid = threadIdx.x;
    __shared__ int sums[256];
    int v[8]; int cnt = 0;
    const int base = b * SEQ + tid * 8;
    #pragma unroll
    for (int e = 0; e < 8; ++e) { v[e] = (mask[base + e] != 0) ? 1 : 0; cnt += v[e]; }
    sums[tid] = cnt;
    __syncthreads();
    for (int off = 1; off < 256; off <<= 1) {
        int t = (tid >= off) ? sums[tid - off] : 0;
        __syncthreads();
        sums[tid] += t;
        __syncthreads();
    }
    int run = sums[tid] - cnt;           // exclusive prefix
    #pragma unroll
    for (int e = 0; e < 8; ++e) { pos[base + e] = run; run += v[e]; }
    if (tid == 255) nc[b] = sums[255];
}

// ---------------------------------------------------------------------------
// fp32 [rows][1024] -> bf16 [rows][3072] along K (GEMM operand), row-XOR
// swizzle baked in. LOSEG: which K-third carries the lo residual.
//   activations LOSEG=1 -> [hi | lo | hi],  weights LOSEG=2 -> [hi | hi | lo]
// ---------------------------------------------------------------------------
template <int LOSEG>
__global__ __launch_bounds__(256) void conv_hilo_kernel(
    const float* __restrict__ src, unsigned short* __restrict__ dst, int rows)
{
    const int id = blockIdx.x * 256 + threadIdx.x;
    if (id >= rows * 384) return;
    const int row = id / 384;
    const int s   = id - row * 384;
    const int g   = s >> 3, ss = s & 7;
    const int lb  = ss ^ (row & 7);
    const int srcg = g & 15;
    const bool lo = ((g >> 4) == LOSEG);

    const float* p = src + (size_t)row * 1024 + srcg * 64 + lb * 8;
    const float4 a = *(const float4*)p;
    const float4 bq = *(const float4*)(p + 4);
    const float xs[8] = {a.x, a.y, a.z, a.w, bq.x, bq.y, bq.z, bq.w};
    us8 o;
    #pragma unroll
    for (int e = 0; e < 8; ++e) {
        float x = xs[e];
        if (lo) { unsigned short h = f2b(x); x = x - b2f(h); }
        o[e] = f2b(x);
    }
    *(us8*)&dst[(size_t)row * 3072 + s * 8] = o;
}

// ---------------------------------------------------------------------------
// bf16 MFMA GEMM, 128x64 tile (grid 32x16 = 512 blocks -> 2/CU), BK=64,
// 4 waves x (64x32), double-buffered LDS, global_load_lds x16B.
// MODE epilogue: 0: fp32 [M][1024]   1: fp32 split [b][h][s][dk]
//  2: K2  bf16 [bh][kpos][128] hi|lo (swz), COMPACTED via pos[], masked skip
//  3: VT2 bf16 [bh][d][2048] key-block swz, COMPACTED via pos[], masked skip
// ---------------------------------------------------------------------------
template <int MODE>
__global__ __launch_bounds__(256) void mfma_gemm_kernel(
    const unsigned short* __restrict__ A2, const unsigned short* __restrict__ W2,
    const float* __restrict__ bias, float* __restrict__ Cf,
    unsigned short* __restrict__ Cb,
    const int* __restrict__ mask, const int* __restrict__ pos)
{
    constexpr int K3 = 3072;
    __shared__ bf16x8 Asl[2][1024];   // 128 rows x 8 x 16B
    __shared__ bf16x8 Bsl[2][512];    // 64 rows x 8 x 16B

    const int tid = threadIdx.x;
    const int wv = tid >> 6, ln = tid & 63;
    const int wm = wv >> 1, wn = wv & 1;
    const int bm = blockIdx.x * 128, bn = blockIdx.y * 64;
    const int x = ln & 15, y = ln >> 4;

    f32x4 acc[4][2] = {};

    const unsigned short* Ab = A2 + (size_t)bm * K3;
    const unsigned short* Bb = W2 + (size_t)bn * K3;
    const int srow = ln >> 3;
    const int scol = (ln & 7) * 8;

    auto stage = [&](int bufi, int kt) {
        #pragma unroll
        for (int c = 0; c < 4; ++c) {
            const int rowb = wv * 32 + c * 8;
            gl_lds16(Ab + (size_t)(rowb + srow) * K3 + kt * 64 + scol,
                     (unsigned short*)&Asl[bufi][rowb << 3]);
        }
        #pragma unroll
        for (int c = 0; c < 2; ++c) {
            const int rowb = wv * 16 + c * 8;
            gl_lds16(Bb + (size_t)(rowb + srow) * K3 + kt * 64 + scol,
                     (unsigned short*)&Bsl[bufi][rowb << 3]);
        }
    };

    stage(0, 0);
    asm volatile("s_waitcnt vmcnt(0)" ::: "memory");
    __syncthreads();

    int buf = 0;
    for (int kt = 0; kt < 48; ++kt) {
        if (kt < 47) stage(buf ^ 1, kt + 1);
        #pragma unroll
        for (int half = 0; half < 2; ++half) {
            bf16x8 af[4], bfr[2];
            #pragma unroll
            for (int mf = 0; mf < 4; ++mf) {
                const int r = wm * 64 + mf * 16 + x;
                af[mf] = Asl[buf][(r << 3) | ((half * 4 + y) ^ (r & 7))];
            }
            #pragma unroll
            for (int nf = 0; nf < 2; ++nf) {
                const int r = wn * 32 + nf * 16 + x;
                bfr[nf] = Bsl[buf][(r << 3) | ((half * 4 + y) ^ (r & 7))];
            }
            #pragma unroll
            for (int mf = 0; mf < 4; ++mf)
                #pragma unroll
                for (int nf = 0; nf < 2; ++nf)
                    acc[mf][nf] = __builtin_amdgcn_mfma_f32_16x16x32_bf16(
                        af[mf], bfr[nf], acc[mf][nf], 0, 0, 0);
        }
        asm volatile("s_waitcnt vmcnt(0)" ::: "memory");
        __syncthreads();
        buf ^= 1;
    }

    // epilogue: C/D layout col=lane&15 (n), row=(lane>>4)*4+r (m)
    #pragma unroll
    for (int nf = 0; nf < 2; ++nf) {
        const int n = bn + wn * 32 + nf * 16 + x;
        const float bv = bias[n];
        #pragma unroll
        for (int mf = 0; mf < 4; ++mf) {
            const int mbase = bm + wm * 64 + mf * 16 + y * 4;
            #pragma unroll
            for (int r = 0; r < 4; ++r) {
                const int m = mbase + r;
                const float v = acc[mf][nf][r] + bv;
                const int b = m >> 11, s = m & (SEQ - 1);
                const int hh = n >> 6, dd = n & 63;
                if (MODE == 0) {
                    Cf[(size_t)m * D_MODEL + n] = v;
                } else if (MODE == 1) {
                    Cf[((size_t)((b * NUM_HEADS + hh) * SEQ + s)) * DK + dd] = v;
                } else if (MODE == 2) {
                    if (mask[b * SEQ + s]) {
                        const int p = pos[b * SEQ + s];
                        const unsigned short hi = f2b(v);
                        const unsigned short lo = f2b(v - b2f(hi));
                        const int blk = (dd >> 3) ^ (p & 7), i = dd & 7;
                        unsigned short* kp = Cb +
                            ((size_t)((b * NUM_HEADS + hh) * SEQ + p)) * 128;
                        kp[blk * 8 + i] = hi;
                        kp[64 + blk * 8 + i] = lo;
                    }
                } else {
                    if (mask[b * SEQ + s]) {
                        const int p = pos[b * SEQ + s];
                        const int tile = p >> 6, w = p & 63;
                        const int blk = (w >> 3) ^ (dd & 7), i = w & 7;
                        Cb[((size_t)((b * NUM_HEADS + hh) * DK + dd)) * SEQ +
                           tile * 64 + blk * 8 + i] = f2b(v);
                    }
                }
            }
        }
    }
}

// ---------------------------------------------------------------------------
// MFMA flash attention over COMPACTED keys (nc[b] valid keys, no mask logic).
// Block = 4 waves, one (b,h) x 64-q-row tile; wave owns 16 q rows.
// 1/sqrt(dk) folded into Q fragments. Tail tile: kidx >= nc -> -1e30 (exp->0).
// ---------------------------------------------------------------------------
__global__ __launch_bounds__(256, 3) void attn_mfma_kernel(
    const float* __restrict__ Q, const unsigned short* __restrict__ K2,
    const unsigned short* __restrict__ VT2, const int* __restrict__ ncArr,
    float* __restrict__ CTX)
{
    __shared__ __align__(16) unsigned short SM[16384];   // 32 KB
    unsigned short* Khi = SM;            // [64 key][64 dk] (swz)
    unsigned short* Klo = SM + 4096;
    unsigned short* VTs = SM + 8192;     // [64 d][64 key] (swz)

    const int tid = threadIdx.x;
    const int wave = tid >> 6, lane = tid & 63;
    const int lo4 = lane & 15, hi4 = lane >> 4;
    unsigned short* Pw = SM + 12288 + wave * 1024;  // [16 q][64 key] bf16

    const int orig = blockIdx.x;
    const int swz = (orig & 7) * 128 + (orig >> 3);  // 1024%8==0: bijective
    const int bh = swz >> 5, qblk = swz & 31;
    const int b = bh >> 4, h = bh & 15;

    const float* Qb = Q + (size_t)bh * SEQ * DK;
    const unsigned short* Kb = K2 + (size_t)bh * SEQ * 128;
    const unsigned short* Vb = VT2 + (size_t)bh * DK * SEQ;

    const int ncb = ncArr[b];
    const int ntiles = (ncb + 63) >> 6;

    // Q fragments (hi/lo of q/8): row = q = lane&15, k = (lane>>4)*8+i
    const int qr = qblk * 64 + wave * 16 + lo4;
    bf16x8 qhi[2], qlo[2];
    #pragma unroll
    for (int c = 0; c < 2; ++c) {
        const float* qp = &Qb[(size_t)qr * DK + c * 32 + hi4 * 8];
        const float4 x0 = *(const float4*)qp;
        const float4 x1 = *(const float4*)(qp + 4);
        const float xs[8] = {x0.x, x0.y, x0.z, x0.w, x1.x, x1.y, x1.z, x1.w};
        #pragma unroll
        for (int i = 0; i < 8; ++i) {
            const float sx = xs[i] * 0.125f;
            const unsigned short hh = f2b(sx);
            qhi[c][i] = (short)hh;
            qlo[c][i] = (short)f2b(sx - b2f(hh));
        }
    }

    f32x4 ctx[4] = {};   // ctx^T frags: row d = dt*16+hi4*4+r, col q = lo4
    float m = -INFINITY, l = 0.f;

    for (int t = 0; t < ntiles; ++t) {
        const int k0 = t * 64;
        __syncthreads();
        // stage 24 KB: Khi(512 x16B) | Klo(512) | VT(512)
        #pragma unroll
        for (int j = 0; j < 6; ++j) {
            const int g = j * 256 + wave * 64;   // wave-uniform
            const int gi = g + lane;
            const unsigned short* src;
            if (gi < 512) {
                src = Kb + (size_t)(k0 + (gi >> 3)) * 128 + (gi & 7) * 8;
            } else if (gi < 1024) {
                const int g2 = gi - 512;
                src = Kb + (size_t)(k0 + (g2 >> 3)) * 128 + 64 + (g2 & 7) * 8;
            } else {
                const int g3 = gi - 1024;
                src = Vb + (size_t)(g3 >> 3) * SEQ + k0 + (g3 & 7) * 8;
            }
            gl_lds16(src, SM + (size_t)g * 8);
        }
        asm volatile("s_waitcnt vmcnt(0)" ::: "memory");
        __syncthreads();

        // S^T = K . Q^T : rows = key, cols = q (hi/lo 3-term, fp32-accurate)
        f32x4 sc[4];
        #pragma unroll
        for (int kt = 0; kt < 4; ++kt) {
            f32x4 s = {0.f, 0.f, 0.f, 0.f};
            const int row = kt * 16 + lo4;
            const int rx = row & 7;
            #pragma unroll
            for (int c = 0; c < 2; ++c) {
                const int blk = ((c * 4 + hi4) ^ rx) * 8;
                const bf16x8 kh = *(bf16x8*)&Khi[row * 64 + blk];
                const bf16x8 kl = *(bf16x8*)&Klo[row * 64 + blk];
                s = __builtin_amdgcn_mfma_f32_16x16x32_bf16(kh, qhi[c], s, 0, 0, 0);
                s = __builtin_amdgcn_mfma_f32_16x16x32_bf16(kl, qhi[c], s, 0, 0, 0);
                s = __builtin_amdgcn_mfma_f32_16x16x32_bf16(kh, qlo[c], s, 0, 0, 0);
            }
            sc[kt] = s;
        }

        // row-max; tail tile masks invalid keys (kidx >= ncb) to -1e30
        float cmax = -1e30f;
        if (k0 + 64 <= ncb) {
            #pragma unroll
            for (int kt = 0; kt < 4; ++kt)
                #pragma unroll
                for (int r = 0; r < 4; ++r) cmax = fmaxf(cmax, sc[kt][r]);
        } else {
            #pragma unroll
            for (int kt = 0; kt < 4; ++kt)
                #pragma unroll
                for (int r = 0; r < 4; ++r) {
                    const int kidx = k0 + kt * 16 + hi4 * 4 + r;
                    const float sv = (kidx < ncb) ? sc[kt][r] : -1e30f;
                    sc[kt][r] = sv;
                    cmax = fmaxf(cmax, sv);
                }
        }
        cmax = fmaxf(cmax, __shfl_xor(cmax, 16));
        cmax = fmaxf(cmax, __shfl_xor(cmax, 32));

        const float mnew = fmaxf(m, cmax);
        const float e1 = __expf(m - mnew);   // m=-inf pre-first-tile -> 0
        m = mnew;

        float ps = 0.f;
        #pragma unroll
        for (int kt = 0; kt < 4; ++kt) {
            const float pv0 = __expf(sc[kt][0] - mnew);  // -1e30 -> exp = 0
            const float pv1 = __expf(sc[kt][1] - mnew);
            const float pv2 = __expf(sc[kt][2] - mnew);
            const float pv3 = __expf(sc[kt][3] - mnew);
            ps += (pv0 + pv1) + (pv2 + pv3);
            const unsigned w0 = (unsigned)f2b(pv0) | ((unsigned)f2b(pv1) << 16);
            const unsigned w1 = (unsigned)f2b(pv2) | ((unsigned)f2b(pv3) << 16);
            const int blk16 = (kt * 2 + (hi4 >> 1)) ^ (lo4 & 7);
            unsigned* dst = (unsigned*)&Pw[lo4 * 64 + blk16 * 8 + (hi4 & 1) * 4];
            dst[0] = w0; dst[1] = w1;
        }
        ps += __shfl_xor(ps, 16);
        ps += __shfl_xor(ps, 32);
        l = l * e1 + ps;

        #pragma unroll
        for (int dt = 0; dt < 4; ++dt)
            #pragma unroll
            for (int r = 0; r < 4; ++r) ctx[dt][r] *= e1;

        // ctx^T += V^T . P^T  (same-wave LDS RAW: DS pipe is in-order)
        #pragma unroll
        for (int c = 0; c < 2; ++c) {
            const bf16x8 pf =
                *(bf16x8*)&Pw[lo4 * 64 + (((c * 4 + hi4) ^ (lo4 & 7)) * 8)];
            #pragma unroll
            for (int dt = 0; dt < 4; ++dt) {
                const int row = dt * 16 + lo4;
                const bf16x8 vf =
                    *(bf16x8*)&VTs[row * 64 + (((c * 4 + hi4) ^ (row & 7)) * 8)];
                ctx[dt] = __builtin_amdgcn_mfma_f32_16x16x32_bf16(vf, pf, ctx[dt], 0, 0, 0);
            }
        }
    }

    // epilogue: normalize, transpose via LDS (stride 68 kills 16-way bank
    // conflict), coalesced store
    __syncthreads();
    const float inv = (l > 0.f) ? (1.f / l) : 0.f;   // l==0: fully masked -> 0
    float* OutL = (float*)SM;                        // [64 q][68] fp32, 17.4 KB
    #pragma unroll
    for (int dt = 0; dt < 4; ++dt)
        #pragma unroll
        for (int r = 0; r < 4; ++r)
            OutL[(wave * 16 + lo4) * 68 + dt * 16 + hi4 * 4 + r] = ctx[dt][r] * inv;
    __syncthreads();
    {
        const int row = tid >> 2, cb = (tid & 3) * 16;
        float* dst = CTX + ((size_t)(b * SEQ + qblk * 64 + row)) * D_MODEL
                         + h * DK + cb;
        #pragma unroll
        for (int u = 0; u < 4; ++u)
            *(float4*)&dst[u * 4] = *(float4*)&OutL[row * 68 + cb + u * 4];
    }
}

// ---------------------------------------------------------------------------
// fp32 fallback path (only if ws too small)
// ---------------------------------------------------------------------------
template <int SPLIT>
__global__ __launch_bounds__(256) void gemm_bias_kernel(
    const float* __restrict__ A, const float* __restrict__ W,
    const float* __restrict__ bias, float* __restrict__ C,
    int M, int N, int K)
{
    constexpr int TILE = 64, KT = 16;
    __shared__ float As[KT][TILE + 4];
    __shared__ float Ws[KT][TILE + 4];
    const int tid = threadIdx.x;
    const int tx = tid & 15, ty = tid >> 4;
    const int bm = blockIdx.x * TILE, bn = blockIdx.y * TILE;
    const int lrow = tid >> 2, lk4 = (tid & 3) << 2;
    float acc[4][4] = {{0.f}};
    for (int k0 = 0; k0 < K; k0 += KT) {
        const float4 a4 = *(const float4*)&A[(size_t)(bm + lrow) * K + k0 + lk4];
        const float4 w4 = *(const float4*)&W[(size_t)(bn + lrow) * K + k0 + lk4];
        __syncthreads();
        As[lk4 + 0][lrow] = a4.x; As[lk4 + 1][lrow] = a4.y;
        As[lk4 + 2][lrow] = a4.z; As[lk4 + 3][lrow] = a4.w;
        Ws[lk4 + 0][lrow] = w4.x; Ws[lk4 + 1][lrow] = w4.y;
        Ws[lk4 + 2][lrow] = w4.z; Ws[lk4 + 3][lrow] = w4.w;
        __syncthreads();
        #pragma unroll
        for (int kk = 0; kk < KT; ++kk) {
            const float4 av = *(const float4*)&As[kk][ty << 2];
            const float4 wv = *(const float4*)&Ws[kk][tx << 2];
            acc[0][0] += av.x * wv.x; acc[0][1] += av.x * wv.y; acc[0][2] += av.x * wv.z; acc[0][3] += av.x * wv.w;
            acc[1][0] += av.y * wv.x; acc[1][1] += av.y * wv.y; acc[1][2] += av.y * wv.z; acc[1][3] += av.y * wv.w;
            acc[2][0] += av.z * wv.x; acc[2][1] += av.z * wv.y; acc[2][2] += av.z * wv.z; acc[2][3] += av.z * wv.w;
            acc[3][0] += av.w * wv.x; acc[3][1] += av.w * wv.y; acc[3][2] += av.w * wv.z; acc[3][3] += av.w * wv.w;
        }
    }
    const float4 bb = *(const float4*)&bias[bn + (tx << 2)];
    #pragma unroll
    for (int i = 0; i < 4; ++i) {
        const int row = bm + (ty << 2) + i;
        float4 o;
        o.x = acc[i][0] + bb.x; o.y = acc[i][1] + bb.y;
        o.z = acc[i][2] + bb.z; o.w = acc[i][3] + bb.w;
        if (SPLIT) {
            const int b = row >> 11, s = row & (SEQ - 1), hh = bn >> 6;
            *(float4*)&C[((size_t)((b * NUM_HEADS + hh) * SEQ + s)) * DK + (tx << 2)] = o;
        } else {
            *(float4*)&C[(size_t)row * N + bn + (tx << 2)] = o;
        }
    }
}

__global__ __launch_bounds__(256, 2) void attn_fp32_kernel(
    const float* __restrict__ Q, const float* __restrict__ K,
    const float* __restrict__ V, const int* __restrict__ mask,
    float* __restrict__ OUT)
{
    const int qb = blockIdx.x, h = blockIdx.y, b = blockIdx.z;
    const int wave = threadIdx.x >> 6, lane = threadIdx.x & 63;
    const int tid = threadIdx.x;
    const int bh = b * NUM_HEADS + h;
    const float* Qb = Q + (size_t)bh * SEQ * DK;
    const float* Kb = K + (size_t)bh * SEQ * DK;
    const float* Vb = V + (size_t)bh * SEQ * DK;
    const int* mb = mask + b * SEQ;
    __shared__ float Ks[64][68];
    __shared__ float Vs[64][68];
    const int row = qb * 256 + wave * 64 + lane;
    float q[DK], ctx[DK];
    #pragma unroll
    for (int d4 = 0; d4 < 16; ++d4) {
        const float4 t = *(const float4*)&Qb[(size_t)row * DK + 4 * d4];
        q[4*d4] = t.x; q[4*d4+1] = t.y; q[4*d4+2] = t.z; q[4*d4+3] = t.w;
        ctx[4*d4] = 0.f; ctx[4*d4+1] = 0.f; ctx[4*d4+2] = 0.f; ctx[4*d4+3] = 0.f;
    }
    float m = -INFINITY, l = 0.f;
    for (int t = 0; t < SEQ / 64; ++t) {
        const int k0 = t * 64;
        const float* Kt = Kb + (size_t)k0 * DK;
        const float* Vt = Vb + (size_t)k0 * DK;
        __syncthreads();
        #pragma unroll
        for (int i = 0; i < 4; ++i) {
            const int f4 = i * 256 + tid;
            const int r = f4 >> 4, c = (f4 & 15) << 2;
            *(float4*)&Ks[r][c] = *(const float4*)&Kt[4 * f4];
            *(float4*)&Vs[r][c] = *(const float4*)&Vt[4 * f4];
        }
        __syncthreads();
        const unsigned long long mbits = __ballot(mb[k0 + lane] != 0);
        if (mbits == 0ULL) continue;
        for (int c0 = 0; c0 < 64; c0 += 16) {
            const unsigned bits = (unsigned)((mbits >> c0) & 0xFFFFULL);
            if (!bits) continue;
            float sc[16];
            #pragma unroll
            for (int j = 0; j < 16; ++j) {
                if (!((bits >> j) & 1u)) { sc[j] = -INFINITY; continue; }
                float a0 = 0.f, a1 = 0.f, a2 = 0.f, a3 = 0.f;
                #pragma unroll
                for (int d4 = 0; d4 < 16; ++d4) {
                    const float4 kv = *(const float4*)&Ks[c0 + j][4 * d4];
                    a0 += q[4*d4] * kv.x; a1 += q[4*d4+1] * kv.y;
                    a2 += q[4*d4+2] * kv.z; a3 += q[4*d4+3] * kv.w;
                }
                sc[j] = ((a0 + a1) + (a2 + a3)) * 0.125f;
            }
            float cmax = sc[0];
            #pragma unroll
            for (int j = 1; j < 16; ++j) cmax = fmaxf(cmax, sc[j]);
            if (cmax > m) {
                const float scale = __expf(m - cmax);
                l *= scale;
                #pragma unroll
                for (int d = 0; d < DK; ++d) ctx[d] *= scale;
                m = cmax;
            }
            #pragma unroll
            for (int j = 0; j < 16; ++j) {
                if (!((bits >> j) & 1u)) continue;
                const float p = __expf(sc[j] - m);
                l += p;
                #pragma unroll
                for (int d4 = 0; d4 < 16; ++d4) {
                    const float4 vv = *(const float4*)&Vs[c0 + j][4 * d4];
                    ctx[4*d4] += p * vv.x; ctx[4*d4+1] += p * vv.y;
                    ctx[4*d4+2] += p * vv.z; ctx[4*d4+3] += p * vv.w;
                }
            }
        }
    }
    const float inv = (l > 0.f) ? (1.f / l) : 0.f;
    float* dst = OUT + ((size_t)(b * SEQ + row)) * D_MODEL + h * DK;
    #pragma unroll
    for (int d4 = 0; d4 < 16; ++d4) {
        float4 o;
        o.x = ctx[4*d4] * inv; o.y = ctx[4*d4+1] * inv;
        o.z = ctx[4*d4+2] * inv; o.w = ctx[4*d4+3] * inv;
        *(float4*)&dst[4 * d4] = o;
    }
}

// ---------------------------------------------------------------------------
extern "C" void kernel_launch(void* const* d_in, const int* in_sizes, int n_in,
                              void* d_out, int out_size, void* d_ws, size_t ws_size,
                              hipStream_t stream)
{
    const float* query = (const float*)d_in[0];
    const float* key_  = (const float*)d_in[1];
    const float* value = (const float*)d_in[2];
    const int*   mask  = (const int*)d_in[3];
    const float* Wq = (const float*)d_in[4];
    const float* bq = (const float*)d_in[5];
    const float* Wk = (const float*)d_in[6];
    const float* bk = (const float*)d_in[7];
    const float* Wv = (const float*)d_in[8];
    const float* bv = (const float*)d_in[9];
    const float* Wo = (const float*)d_in[10];
    const float* bo = (const float*)d_in[11];
    float* out = (float*)d_out;

    const int M = BATCH * SEQ;                            // 4096
    const size_t PER_B  = (size_t)M * D_MODEL * 4;        // 16 MB
    const size_t ACT2_B = (size_t)M * 3072 * 2;           // 24 MB
    const size_t W2_B   = (size_t)D_MODEL * 3072 * 2;     // 6.3 MB
    const size_t K2_B   = (size_t)32 * SEQ * 128 * 2;     // 16.8 MB
    const size_t VT2_B  = (size_t)32 * DK * SEQ * 2;      // 8.4 MB
    const size_t POS_B  = (size_t)BATCH * SEQ * 4 + 256;  // pos + nc

    char* base = (char*)d_ws;
    float* q_ws = (float*)(base);
    float* c_ws = (float*)(base + PER_B);
    unsigned short* act2 = (unsigned short*)(base + 2 * PER_B);
    unsigned short* w2q = (unsigned short*)(base + 2 * PER_B + ACT2_B);
    unsigned short* w2k = (unsigned short*)((char*)w2q + W2_B);
    unsigned short* w2v = (unsigned short*)((char*)w2k + W2_B);
    unsigned short* w2o = (unsigned short*)((char*)w2v + W2_B);
    unsigned short* k2  = (unsigned short*)((char*)w2o + W2_B);
    unsigned short* vt2 = (unsigned short*)((char*)k2 + K2_B);
    int* posArr = (int*)((char*)vt2 + VT2_B);
    int* ncArr  = posArr + BATCH * SEQ;
    const size_t need = 2 * PER_B + ACT2_B + 4 * W2_B + K2_B + VT2_B + POS_B;

    if (ws_size >= need) {
        mask_scan_kernel<<<BATCH, 256, 0, stream>>>(mask, posArr, ncArr);
        hipMemsetAsync(k2, 0, K2_B, stream);
        hipMemsetAsync(vt2, 0, VT2_B, stream);

        const int wblk = (D_MODEL * 384 + 255) / 256;
        const int ablk = (M * 384 + 255) / 256;
        conv_hilo_kernel<2><<<wblk, 256, 0, stream>>>(Wq, w2q, D_MODEL);
        conv_hilo_kernel<2><<<wblk, 256, 0, stream>>>(Wk, w2k, D_MODEL);
        conv_hilo_kernel<2><<<wblk, 256, 0, stream>>>(Wv, w2v, D_MODEL);
        conv_hilo_kernel<2><<<wblk, 256, 0, stream>>>(Wo, w2o, D_MODEL);

        dim3 ggrid(M / 128, D_MODEL / 64);                // 32,16 = 512 blocks
        conv_hilo_kernel<1><<<ablk, 256, 0, stream>>>(query, act2, M);
        mfma_gemm_kernel<1><<<ggrid, 256, 0, stream>>>(act2, w2q, bq, q_ws, nullptr, nullptr, nullptr);
        conv_hilo_kernel<1><<<ablk, 256, 0, stream>>>(key_, act2, M);
        mfma_gemm_kernel<2><<<ggrid, 256, 0, stream>>>(act2, w2k, bk, nullptr, k2, mask, posArr);
        conv_hilo_kernel<1><<<ablk, 256, 0, stream>>>(value, act2, M);
        mfma_gemm_kernel<3><<<ggrid, 256, 0, stream>>>(act2, w2v, bv, nullptr, vt2, mask, posArr);

        attn_mfma_kernel<<<1024, 256, 0, stream>>>(q_ws, k2, vt2, ncArr, c_ws);

        conv_hilo_kernel<1><<<ablk, 256, 0, stream>>>(c_ws, act2, M);
        mfma_gemm_kernel<0><<<ggrid, 256, 0, stream>>>(act2, w2o, bo, out, nullptr, nullptr, nullptr);
    } else {
        float* k_ws = (float*)(base + 2 * PER_B);
        float* v_ws = (float*)(base + 3 * PER_B);
        dim3 ggrid(M / 64, D_MODEL / 64);
        gemm_bias_kernel<1><<<ggrid, 256, 0, stream>>>(query, Wq, bq, q_ws, M, D_MODEL, D_MODEL);
        gemm_bias_kernel<1><<<ggrid, 256, 0, stream>>>(key_,  Wk, bk, k_ws, M, D_MODEL, D_MODEL);
        gemm_bias_kernel<1><<<ggrid, 256, 0, stream>>>(value, Wv, bv, v_ws, M, D_MODEL, D_MODEL);
        dim3 agrid(SEQ / 256, NUM_HEADS, BATCH);
        attn_fp32_kernel<<<agrid, 256, 0, stream>>>(q_ws, k_ws, v_ws, mask, c_ws);
        gemm_bias_kernel<0><<<ggrid, 256, 0, stream>>>(c_ws, Wo, bo, out, M, D_MODEL, D_MODEL);
    }
}